// Round 4
// baseline (216.286 us; speedup 1.0000x reference)
//
#include <hip/hip_runtime.h>

#define NBH 32      // B*H
#define LL  2048
#define DD  64
#define BQ  64      // q rows per block
#define BK  64      // k tile
#define NT  32      // LL/BK
#define CSHIFT 120.0f

typedef _Float16 f16;
typedef _Float16 f16x4 __attribute__((ext_vector_type(4)));
typedef _Float16 f16x8 __attribute__((ext_vector_type(8)));
typedef _Float16 f16x8a __attribute__((ext_vector_type(8), may_alias));
typedef _Float16 f16x4a __attribute__((ext_vector_type(4), may_alias));
typedef float f32x4 __attribute__((ext_vector_type(4)));

__device__ __forceinline__ float elu1(float x) { return x > 0.f ? x + 1.f : __expf(x); }

__device__ __forceinline__ void gl_lds16(const void* src, void* lds_dst) {
  __builtin_amdgcn_global_load_lds((const __attribute__((address_space(1))) unsigned int*)src,
                                   (__attribute__((address_space(3))) unsigned int*)lds_dst,
                                   16, 0, 0);
}

// Stage a 64-row x 128B tile into 8KB LDS (linear dest). Content is swizzled so
// LDS 16B-slot s of row r holds global slot s^(r&7); readers apply the same XOR.
__device__ __forceinline__ void stage_tile(const char* gbase, size_t grow, f16* lds, int w, int l) {
#pragma unroll
  for (int c2 = 0; c2 < 2; ++c2) {
    int U = w * 128 + c2 * 64 + l;       // 16B unit id
    int r = U >> 3, sp = U & 7;
    gl_lds16(gbase + (size_t)r * grow + ((sp ^ (r & 7)) << 4),
             (char*)lds + w * 2048 + c2 * 1024);   // wave-uniform base; HW adds lane*16
  }
}

// Featurize K -> fp16 and transpose V -> Vt[d][k] fp16, one read pass.
__global__ void prep(const float* __restrict__ K, const float* __restrict__ V,
                     f16* __restrict__ Kf, f16* __restrict__ Vt) {
  __shared__ f16 Lt[64][72];
  const int bh = blockIdx.y, r0 = blockIdx.x * 64;
  const int t = threadIdx.x;
#pragma unroll
  for (int it = 0; it < 4; ++it) {
    int idx = t + 256 * it;
    int r = idx >> 4, d0 = (idx & 15) * 4;
    float4 kv = *(const float4*)(K + (size_t)(bh * LL + r0 + r) * DD + d0);
    f16x4 kh = { (f16)elu1(kv.x), (f16)elu1(kv.y), (f16)elu1(kv.z), (f16)elu1(kv.w) };
    *(f16x4a*)(Kf + (size_t)(bh * LL + r0 + r) * DD + d0) = kh;
    float4 vv = *(const float4*)(V + (size_t)(bh * LL + r0 + r) * DD + d0);
    f16x4 vh = { (f16)vv.x, (f16)vv.y, (f16)vv.z, (f16)vv.w };
    *(f16x4a*)&Lt[r][d0] = vh;
  }
  __syncthreads();
  const int w = t >> 6, l = t & 63;
#pragma unroll
  for (int it = 0; it < 2; ++it) {
    int s = w + 4 * it;
    f16x8 o;
#pragma unroll
    for (int j = 0; j < 8; ++j) o[j] = Lt[8 * s + j][l];
    *(f16x8*)(Vt + (size_t)(bh * DD + l) * LL + r0 + 8 * s) = o;
  }
}

// Fused: loop1 computes 1/rowsum in registers; loop2 recomputes scores
// (bitwise-identical MFMA sequence), writes normalized attn + accumulates PV.
// Operand-swapped MFMAs keep q in the lane column everywhere:
//   QK: acc = mfma(Kfrag, Qfrag) -> lane holds s[k=16n+4g+i][q=16w+c]
//   PV: ctx = mfma(Vfrag, Pfrag) -> lane holds ctx[d=16n+4g+i][q=16w+c]
__launch_bounds__(256, 4)
__global__ void attn_fused(const float* __restrict__ Q, const f16* __restrict__ Kf,
                           const f16* __restrict__ Vt,
                           float* __restrict__ ctx_out, float* __restrict__ attn_out) {
  __shared__ f16 Ks[2][BK * DD];
  __shared__ f16 Vs[2][BK * DD];
  __shared__ f16 Ps[BQ * BK];
  const int bh = blockIdx.y, q0 = blockIdx.x * BQ;
  const int t = threadIdx.x, w = t >> 6, l = t & 63, g = l >> 4, c = l & 15;
  const char* Kh  = (const char*)(Kf + (size_t)bh * LL * DD);
  const char* Vth = (const char*)(Vt + (size_t)bh * DD * LL);
  float* __restrict__ attn_h = attn_out + (size_t)bh * LL * LL;

  // Q fragments straight from global (featurized in-reg). B-operand layout:
  // lane holds Q[row=16w+c][d = 32ka + 8g + j].
  const int qrow = q0 + 16 * w + c;
  f16x8 qf[2];
#pragma unroll
  for (int ka = 0; ka < 2; ++ka) {
    const float* qp = Q + (size_t)(bh * LL + qrow) * DD + 32 * ka + 8 * g;
    float4 a = *(const float4*)qp;
    float4 b = *(const float4*)(qp + 4);
    f16x8 h = { (f16)elu1(a.x), (f16)elu1(a.y), (f16)elu1(a.z), (f16)elu1(a.w),
                (f16)elu1(b.x), (f16)elu1(b.y), (f16)elu1(b.z), (f16)elu1(b.w) };
    qf[ka] = h;
  }

  stage_tile(Kh, 128, Ks[0], w, l);
  __syncthreads();

  // ---- loop 1: rowsum ----
  float rs = 0.f;
  for (int kt = 0; kt < NT; ++kt) {
    if (kt + 1 < NT) {
      stage_tile(Kh + (size_t)(kt + 1) * BK * 128, 128, Ks[(kt + 1) & 1], w, l);
    } else {  // last iter: preload tile 0 of K and V for loop 2
      stage_tile(Kh, 128, Ks[0], w, l);
      stage_tile(Vth, (size_t)LL * 2, Vs[0], w, l);
    }
    const char* Kb = (const char*)Ks[kt & 1];
#pragma unroll
    for (int n = 0; n < 4; ++n) {
      f32x4 acc = {0.f, 0.f, 0.f, 0.f};
#pragma unroll
      for (int ka = 0; ka < 2; ++ka) {
        int row = n * 16 + c;
        f16x8 kfr = (f16x8)(*(const f16x8a*)(Kb + row * 128 + (((4 * ka + g) ^ (row & 7)) << 4)));
        acc = __builtin_amdgcn_mfma_f32_16x16x32_f16(kfr, qf[ka], acc, 0, 0, 0);
      }
#pragma unroll
      for (int i = 0; i < 4; ++i) rs += __expf(acc[i] - CSHIFT);
    }
    __syncthreads();
  }
  rs += __shfl_xor(rs, 16);
  rs += __shfl_xor(rs, 32);
  const float inv = 1.0f / rs;

  // ---- loop 2: recompute, write attn, accumulate PV ----
  f32x4 ctx[4];
#pragma unroll
  for (int n = 0; n < 4; ++n) ctx[n] = (f32x4){0.f, 0.f, 0.f, 0.f};

  for (int kt = 0; kt < NT; ++kt) {
    const int cur = kt & 1;
    if (kt + 1 < NT) {
      stage_tile(Kh + (size_t)(kt + 1) * BK * 128, 128, Ks[cur ^ 1], w, l);
      stage_tile(Vth + (size_t)(kt + 1) * BK * 2, (size_t)LL * 2, Vs[cur ^ 1], w, l);
    }
    const char* Kb = (const char*)Ks[cur];
    const char* Vb = (const char*)Vs[cur];
    float* arow = attn_h + (size_t)qrow * LL + kt * BK;

#pragma unroll
    for (int n = 0; n < 4; ++n) {
      f32x4 acc = {0.f, 0.f, 0.f, 0.f};
#pragma unroll
      for (int ka = 0; ka < 2; ++ka) {
        int row = n * 16 + c;
        f16x8 kfr = (f16x8)(*(const f16x8a*)(Kb + row * 128 + (((4 * ka + g) ^ (row & 7)) << 4)));
        acc = __builtin_amdgcn_mfma_f32_16x16x32_f16(kfr, qf[ka], acc, 0, 0, 0);
      }
      f32x4 p;
#pragma unroll
      for (int i = 0; i < 4; ++i) p[i] = __expf(acc[i] - CSHIFT) * inv;  // normalized, <= 1
      // Plain write-back store: the 64B half-line segments from adjacent n
      // iterations merge in L2 into full 128B lines (nt bypassed L2 -> ~50% eff).
      *(f32x4*)(arow + n * 16 + 4 * g) = p;
      f16x4 ph = { (f16)p[0], (f16)p[1], (f16)p[2], (f16)p[3] };
      *(f16x4a*)((char*)Ps + (16 * w + c) * 128 + ((32 * n + 8 * g) ^ ((c & 7) << 4))) = ph;
    }

    // PV (Ps traffic is wave-local: rows 16w..16w+15 written and read by wave w only)
#pragma unroll
    for (int ka = 0; ka < 2; ++ka) {
      f16x8 pf = (f16x8)(*(const f16x8a*)((const char*)Ps + (16 * w + c) * 128 + (((4 * ka + g) ^ (c & 7)) << 4)));
#pragma unroll
      for (int n = 0; n < 4; ++n) {
        int row = n * 16 + c;
        f16x8 vf = (f16x8)(*(const f16x8a*)(Vb + row * 128 + (((4 * ka + g) ^ (row & 7)) << 4)));
        ctx[n] = __builtin_amdgcn_mfma_f32_16x16x32_f16(vf, pf, ctx[n], 0, 0, 0);
      }
    }
    __syncthreads();
  }

#pragma unroll
  for (int n = 0; n < 4; ++n)
    *(f32x4*)(ctx_out + (size_t)(bh * LL + qrow) * DD + n * 16 + 4 * g) = ctx[n];
}

extern "C" void kernel_launch(void* const* d_in, const int* in_sizes, int n_in,
                              void* d_out, int out_size, void* d_ws, size_t ws_size,
                              hipStream_t stream) {
  const float* Q = (const float*)d_in[0];
  const float* K = (const float*)d_in[1];
  const float* V = (const float*)d_in[2];

  float* ctx_out  = (float*)d_out;                      // [32][2048][64]
  float* attn_out = ctx_out + (size_t)NBH * LL * DD;    // [32][2048][2048]

  f16* Kf = (f16*)d_ws;                                 // featurized K, fp16, 8 MB
  f16* Vt = Kf + (size_t)NBH * LL * DD;                 // V^T per head, fp16, 8 MB

  hipLaunchKernelGGL(prep, dim3(LL / 64, NBH), dim3(256), 0, stream, K, V, Kf, Vt);
  hipLaunchKernelGGL(attn_fused, dim3(LL / BQ, NBH), dim3(256), 0, stream,
                     Q, Kf, Vt, ctx_out, attn_out);
}

// Round 5
// 157.545 us; speedup vs baseline: 1.3729x; 1.3729x over previous
//
#include <hip/hip_runtime.h>

#define NBH 32      // B*H
#define LL  2048
#define DD  64
#define BQ  64      // q rows per block
#define BK  64      // k tile
#define NT  32      // LL/BK
#define CSHIFT 120.0f

typedef _Float16 f16;
typedef _Float16 f16x4 __attribute__((ext_vector_type(4)));
typedef _Float16 f16x8 __attribute__((ext_vector_type(8)));
typedef _Float16 f16x8a __attribute__((ext_vector_type(8), may_alias));
typedef _Float16 f16x4a __attribute__((ext_vector_type(4), may_alias));
typedef float f32x4 __attribute__((ext_vector_type(4)));

__device__ __forceinline__ float elu1(float x) { return x > 0.f ? x + 1.f : __expf(x); }

__device__ __forceinline__ void gl_lds16(const void* src, void* lds_dst) {
  __builtin_amdgcn_global_load_lds((const __attribute__((address_space(1))) unsigned int*)src,
                                   (__attribute__((address_space(3))) unsigned int*)lds_dst,
                                   16, 0, 0);
}

// Stage a 64-row x 128B tile into 8KB LDS (linear dest). Content is swizzled so
// LDS 16B-slot s of row r holds global slot s^(r&7); readers apply the same XOR.
__device__ __forceinline__ void stage_tile(const char* gbase, size_t grow, f16* lds, int w, int l) {
#pragma unroll
  for (int c2 = 0; c2 < 2; ++c2) {
    int U = w * 128 + c2 * 64 + l;       // 16B unit id
    int r = U >> 3, sp = U & 7;
    gl_lds16(gbase + (size_t)r * grow + ((sp ^ (r & 7)) << 4),
             (char*)lds + w * 2048 + c2 * 1024);   // wave-uniform base; HW adds lane*16
  }
}

// Featurize K -> fp16 and transpose V -> Vt[d][k] fp16, one read pass.
__global__ void prep(const float* __restrict__ K, const float* __restrict__ V,
                     f16* __restrict__ Kf, f16* __restrict__ Vt) {
  __shared__ f16 Lt[64][72];
  const int bh = blockIdx.y, r0 = blockIdx.x * 64;
  const int t = threadIdx.x;
#pragma unroll
  for (int it = 0; it < 4; ++it) {
    int idx = t + 256 * it;
    int r = idx >> 4, d0 = (idx & 15) * 4;
    float4 kv = *(const float4*)(K + (size_t)(bh * LL + r0 + r) * DD + d0);
    f16x4 kh = { (f16)elu1(kv.x), (f16)elu1(kv.y), (f16)elu1(kv.z), (f16)elu1(kv.w) };
    *(f16x4a*)(Kf + (size_t)(bh * LL + r0 + r) * DD + d0) = kh;
    float4 vv = *(const float4*)(V + (size_t)(bh * LL + r0 + r) * DD + d0);
    f16x4 vh = { (f16)vv.x, (f16)vv.y, (f16)vv.z, (f16)vv.w };
    *(f16x4a*)&Lt[r][d0] = vh;
  }
  __syncthreads();
  const int w = t >> 6, l = t & 63;
#pragma unroll
  for (int it = 0; it < 2; ++it) {
    int s = w + 4 * it;
    f16x8 o;
#pragma unroll
    for (int j = 0; j < 8; ++j) o[j] = Lt[8 * s + j][l];
    *(f16x8*)(Vt + (size_t)(bh * DD + l) * LL + r0 + 8 * s) = o;
  }
}

// Fused: loop1 computes 1/rowsum in registers; loop2 recomputes scores
// (bitwise-identical MFMA sequence), writes normalized attn + accumulates PV.
// Operand-swapped MFMAs keep q in the lane column everywhere:
//   QK: acc = mfma(Kfrag, Qfrag) -> lane holds s[k=16n+4g+i][q=16w+c]
//   PV: ctx = mfma(Vfrag, Pfrag) -> lane holds ctx[d=16n+4g+i][q=16w+c]
// P tile goes through LDS (fp16, swizzled) so attn stores are full-line
// contiguous (1KB/wave-inst) nontemporal: no RFO (R4 lesson), no partial lines
// (R3 lesson).
__launch_bounds__(256, 4)
__global__ void attn_fused(const float* __restrict__ Q, const f16* __restrict__ Kf,
                           const f16* __restrict__ Vt,
                           float* __restrict__ ctx_out, float* __restrict__ attn_out) {
  __shared__ f16 Ks[2][BK * DD];
  __shared__ f16 Vs[2][BK * DD];
  __shared__ f16 Pf[BQ * BK];   // P tile, [q][k] fp16, 16B-slot swizzle: phys = slot^(q&7)
  const int bh = blockIdx.y, q0 = blockIdx.x * BQ;
  const int t = threadIdx.x, w = t >> 6, l = t & 63, g = l >> 4, c = l & 15;
  const char* Kh  = (const char*)(Kf + (size_t)bh * LL * DD);
  const char* Vth = (const char*)(Vt + (size_t)bh * DD * LL);
  float* __restrict__ attn_h = attn_out + (size_t)bh * LL * LL;

  // Q fragments straight from global (featurized in-reg). B-operand layout:
  // lane holds Q[row=16w+c][d = 32ka + 8g + j].
  const int qrow = q0 + 16 * w + c;
  f16x8 qf[2];
#pragma unroll
  for (int ka = 0; ka < 2; ++ka) {
    const float* qp = Q + (size_t)(bh * LL + qrow) * DD + 32 * ka + 8 * g;
    float4 a = *(const float4*)qp;
    float4 b = *(const float4*)(qp + 4);
    f16x8 h = { (f16)elu1(a.x), (f16)elu1(a.y), (f16)elu1(a.z), (f16)elu1(a.w),
                (f16)elu1(b.x), (f16)elu1(b.y), (f16)elu1(b.z), (f16)elu1(b.w) };
    qf[ka] = h;
  }

  stage_tile(Kh, 128, Ks[0], w, l);
  __syncthreads();

  // ---- loop 1: rowsum ----
  float rs = 0.f;
  for (int kt = 0; kt < NT; ++kt) {
    if (kt + 1 < NT) {
      stage_tile(Kh + (size_t)(kt + 1) * BK * 128, 128, Ks[(kt + 1) & 1], w, l);
    } else {  // last iter: preload tile 0 of K and V for loop 2
      stage_tile(Kh, 128, Ks[0], w, l);
      stage_tile(Vth, (size_t)LL * 2, Vs[0], w, l);
    }
    const char* Kb = (const char*)Ks[kt & 1];
#pragma unroll
    for (int n = 0; n < 4; ++n) {
      f32x4 acc = {0.f, 0.f, 0.f, 0.f};
#pragma unroll
      for (int ka = 0; ka < 2; ++ka) {
        int row = n * 16 + c;
        f16x8 kfr = (f16x8)(*(const f16x8a*)(Kb + row * 128 + (((4 * ka + g) ^ (row & 7)) << 4)));
        acc = __builtin_amdgcn_mfma_f32_16x16x32_f16(kfr, qf[ka], acc, 0, 0, 0);
      }
#pragma unroll
      for (int i = 0; i < 4; ++i) rs += __expf(acc[i] - CSHIFT);
    }
    __syncthreads();
  }
  rs += __shfl_xor(rs, 16);
  rs += __shfl_xor(rs, 32);
  const float inv = 1.0f / rs;

  // ---- loop 2: recompute, write attn (via LDS transpose), accumulate PV ----
  f32x4 ctx[4];
#pragma unroll
  for (int n = 0; n < 4; ++n) ctx[n] = (f32x4){0.f, 0.f, 0.f, 0.f};

  for (int kt = 0; kt < NT; ++kt) {
    const int cur = kt & 1;
    if (kt + 1 < NT) {
      stage_tile(Kh + (size_t)(kt + 1) * BK * 128, 128, Ks[cur ^ 1], w, l);
      stage_tile(Vth + (size_t)(kt + 1) * BK * 2, (size_t)LL * 2, Vs[cur ^ 1], w, l);
    }
    const char* Kb = (const char*)Ks[cur];
    const char* Vb = (const char*)Vs[cur];

#pragma unroll
    for (int n = 0; n < 4; ++n) {
      f32x4 acc = {0.f, 0.f, 0.f, 0.f};
#pragma unroll
      for (int ka = 0; ka < 2; ++ka) {
        int row = n * 16 + c;
        f16x8 kfr = (f16x8)(*(const f16x8a*)(Kb + row * 128 + (((4 * ka + g) ^ (row & 7)) << 4)));
        acc = __builtin_amdgcn_mfma_f32_16x16x32_f16(kfr, qf[ka], acc, 0, 0, 0);
      }
      f32x4 p;
#pragma unroll
      for (int i = 0; i < 4; ++i) p[i] = __expf(acc[i] - CSHIFT) * inv;  // normalized, <= 1
      // P[q=16w+c][k=16n+4g+i] as fp16 into swizzled LDS (wave-local rows).
      f16x4 ph = { (f16)p[0], (f16)p[1], (f16)p[2], (f16)p[3] };
      int slot = (2 * n + (g >> 1)) ^ (c & 7);
      *(f16x4a*)((char*)Pf + (16 * w + c) * 128 + slot * 16 + (g & 1) * 8) = ph;
    }

    // PV: A-fragment = one b128 from Pf (lane needs P[k=32ka+8g+j][q=16w+c])
#pragma unroll
    for (int ka = 0; ka < 2; ++ka) {
      f16x8 pf = (f16x8)(*(const f16x8a*)((const char*)Pf + (16 * w + c) * 128 + (((4 * ka + g) ^ (c & 7)) << 4)));
#pragma unroll
      for (int n = 0; n < 4; ++n) {
        int row = n * 16 + c;
        f16x8 vf = (f16x8)(*(const f16x8a*)(Vb + row * 128 + (((4 * ka + g) ^ (row & 7)) << 4)));
        ctx[n] = __builtin_amdgcn_mfma_f32_16x16x32_f16(vf, pf, ctx[n], 0, 0, 0);
      }
    }

    // attn store: b64 LDS read + cvt + nt f32x4 store; wave covers 1KB contiguous
    // (4 rows x 256B, full 128B lines). Rows 16w..16w+15 are wave-local.
    float* abase = attn_h + (size_t)q0 * LL + kt * BK;
#pragma unroll
    for (int it = 0; it < 4; ++it) {
      int r_loc = 16 * w + 4 * it + (l >> 4);
      int u = l & 15;                      // 8B unit within the 128B row
      int phys = (((u >> 1) ^ (r_loc & 7)) << 4) + (u & 1) * 8;
      f16x4 hv = *(const f16x4a*)((const char*)Pf + r_loc * 128 + phys);
      f32x4 sv = { (float)hv[0], (float)hv[1], (float)hv[2], (float)hv[3] };
      __builtin_nontemporal_store(sv, (f32x4*)(abase + (size_t)r_loc * LL + 4 * u));
    }
    __syncthreads();
  }

#pragma unroll
  for (int n = 0; n < 4; ++n)
    *(f32x4*)(ctx_out + (size_t)(bh * LL + qrow) * DD + n * 16 + 4 * g) = ctx[n];
}

extern "C" void kernel_launch(void* const* d_in, const int* in_sizes, int n_in,
                              void* d_out, int out_size, void* d_ws, size_t ws_size,
                              hipStream_t stream) {
  const float* Q = (const float*)d_in[0];
  const float* K = (const float*)d_in[1];
  const float* V = (const float*)d_in[2];

  float* ctx_out  = (float*)d_out;                      // [32][2048][64]
  float* attn_out = ctx_out + (size_t)NBH * LL * DD;    // [32][2048][2048]

  f16* Kf = (f16*)d_ws;                                 // featurized K, fp16, 8 MB
  f16* Vt = Kf + (size_t)NBH * LL * DD;                 // V^T per head, fp16, 8 MB

  hipLaunchKernelGGL(prep, dim3(LL / 64, NBH), dim3(256), 0, stream, K, V, Kf, Vt);
  hipLaunchKernelGGL(attn_fused, dim3(LL / BQ, NBH), dim3(256), 0, stream,
                     Q, Kf, Vt, ctx_out, attn_out);
}